// Round 7
// baseline (950.739 us; speedup 1.0000x reference)
//
#include <hip/hip_runtime.h>
#include <hip/hip_bf16.h>

#define BATCH 32
#define T 1024
#define G 4                       // pipeline stages (blocks) per batch
#define CPB (T / G)               // 256 columns per block
#define NTH 256                   // threads per block, 1 column each
#define WVS 4                     // waves per block
#define KS 8                      // steps between barriers / edge chunk rows
#define DOW (63 + KS)             // 71: inter-wave step offset
#define SKEW (DOW * (WVS - 1) + 63)   // 276
#define TOT (SKEW + T)            // 1300
#define NB ((TOT + KS - 1) / KS)  // 163 windows
#define NCHUNK (T / KS)           // 128 flag chunks per interface
#define BIGF 1e10f
#define K2f 14.426950408889634f   // 1/(gamma*ln2), gamma=0.1
#define GLN2f 0.0693147180559945f // gamma*ln2
#define KQTSE_ 0.1f

// workspace layout (bytes)
#define EDGE_FLOATS (BATCH * (G - 1) * T)       // 98304 floats
#define FLAG_OFF (EDGE_FLOATS * 4)              // 393216
#define FLAG_INTS (BATCH * (G - 1) * NCHUNK)    // 12288 ints
#define SDTW_OFF (FLAG_OFF + FLAG_INTS * 4)     // 442368
#define WS_NEEDED (size_t)(SDTW_OFF + BATCH * 4)

// Exact softmin_gamma(a,b,c) via sorted args: m - g*ln(1 + 2^{K(m-md)} + 2^{K(m-M)})
__device__ __forceinline__ float softmin3(float a, float b, float c) {
    float m  = fminf(fminf(a, b), c);             // v_min3_f32
    float M  = fmaxf(fmaxf(a, b), c);             // v_max3_f32
    float md = __builtin_amdgcn_fmed3f(a, b, c);  // v_med3_f32
    float e1 = exp2f((m - md) * K2f);
    float e2 = exp2f((m - M) * K2f);
    return fmaf(-GLN2f, __log2f(1.0f + e1 + e2), m);
}

__global__ void reset_kernel(int* __restrict__ flags) {
    int i = blockIdx.x * 256 + threadIdx.x;
    if (i < FLAG_INTS) flags[i] = 0;
}

// Cross-block pipelined wave-systolic soft-DTW.
// Block (b,g) owns columns [g*256, (g+1)*256), 1 col/thread, 4 waves.
// Intra-block: identical scheme to the proven R5/R6 kernel (shfl left edges,
// LDS ring between waves, one barrier per KS=8 steps, DOW=71).
// Inter-block: panel g's rightmost column streams to panel g+1 via a global
// edge buffer; 8-row chunks published with agent-scope release flags, consumed
// with acquire + one-window-ahead prefetch (latency hidden under compute).
__global__ __launch_bounds__(NTH) void sdtw_pipe_kernel(const float* __restrict__ pred,
                                                        const float* __restrict__ targ,
                                                        float* __restrict__ edges,
                                                        int* __restrict__ flags,
                                                        float* __restrict__ sdtw_out) {
    __shared__ float p[T];
    __shared__ float ring[WVS - 1][T];

    const int blk = blockIdx.x;
    const int b = blk & (BATCH - 1);   // same-batch stages land on one XCD
    const int g = blk >> 5;
    const int tid = threadIdx.x;
    const int wv = tid >> 6;
    const int ln = tid & 63;
    const int myoff = DOW * wv + ln;

    ((float4*)p)[tid] = ((const float4*)(pred + b * T))[tid];
    const float tc = targ[b * T + g * CPB + tid];

    const bool is_consumer = (g > 0) && (tid == 0);
    int* fb_c = flags + ((b * (G - 1)) + (g - 1)) * NCHUNK;
    const float* eb_c = edges + ((b * (G - 1)) + (g - 1)) * T;
    int* fb_p = flags + ((b * (G - 1)) + g) * NCHUNK;
    float* eb_p = edges + ((b * (G - 1)) + g) * T;

    float top = BIGF, cornerR = BIGF, rc = BIGF, result = 0.0f;
    float rlg_cur[KS], rlg_next[KS];
    int flag_next = 0;
#pragma unroll
    for (int i = 0; i < KS; ++i) { rlg_cur[i] = BIGF; rlg_next[i] = BIGF; }

    __syncthreads();

    if (is_consumer) {   // pipeline fill: block until producer's first chunk lands
        while (__hip_atomic_load(&fb_c[0], __ATOMIC_ACQUIRE, __HIP_MEMORY_SCOPE_AGENT) == 0)
            __builtin_amdgcn_s_sleep(2);
#pragma unroll
        for (int i = 0; i < KS; ++i)
            rlg_cur[i] = __hip_atomic_load(&eb_c[i], __ATOMIC_RELAXED, __HIP_MEMORY_SCOPE_AGENT);
        flag_next = __hip_atomic_load(&fb_c[1], __ATOMIC_ACQUIRE, __HIP_MEMORY_SCOPE_AGENT);
    }

    for (int sb = 0; sb < NB; ++sb) {
        const int ics = sb * KS - myoff;

        // lane-0 LDS-ring prefetch for waves 1..3 (identical to proven R6 logic)
        float rl[KS];
#pragma unroll
        for (int so = 0; so < KS; ++so) rl[so] = BIGF;
        if (ln == 0 && wv > 0) {
#pragma unroll
            for (int so = 0; so < KS; ++so) {
                int icc = ics + so;
                icc = icc < 0 ? 0 : (icc >= T ? T - 1 : icc);
                rl[so] = ring[wv - 1][icc];   // garbage if clamped: provably unused
            }
        }

        // consumer: prefetch NEXT window's 8 edge rows + next flag (hidden latency)
        if (is_consumer) {
            const int nb = sb + 1;
            if (nb < NCHUNK) {
                if (flag_next == 0) {
                    while (__hip_atomic_load(&fb_c[nb], __ATOMIC_ACQUIRE, __HIP_MEMORY_SCOPE_AGENT) == 0)
                        __builtin_amdgcn_s_sleep(2);
                }
#pragma unroll
                for (int i = 0; i < KS; ++i)
                    rlg_next[i] = __hip_atomic_load(&eb_c[nb * KS + i], __ATOMIC_RELAXED,
                                                    __HIP_MEMORY_SCOPE_AGENT);
                flag_next = (nb + 1 < NCHUNK)
                    ? __hip_atomic_load(&fb_c[nb + 1], __ATOMIC_ACQUIRE, __HIP_MEMORY_SCOPE_AGENT)
                    : 1;
            }
        }

#pragma unroll
        for (int so = 0; so < KS; ++so) {
            const int ic = ics + so;
            const float sh = __shfl_up(rc, 1, 64);
            float lf;
            if (ln == 0) {
                lf = (wv == 0) ? (g ? rlg_cur[so] : BIGF) : rl[so];
            } else {
                lf = sh;
            }

            if (ic >= 0 && ic < T) {
                const float t0 = (ic == 0) ? BIGF : top;
                const float cc = (ic == 0) ? ((g == 0 && tid == 0) ? 0.0f : BIGF) : cornerR;
                const float d0 = p[ic] - tc;
                const float cell = fmaf(d0, d0, softmin3(cc, t0, lf));
                rc = cell; top = cell; cornerR = lf; result = cell;

                if (ln == 63) {
                    if (wv < WVS - 1) {
                        ring[wv][ic] = cell;                 // intra-block handoff
                    } else if (g < G - 1) {                  // block's rightmost column
                        __hip_atomic_store(&eb_p[ic], cell, __ATOMIC_RELAXED,
                                           __HIP_MEMORY_SCOPE_AGENT);
                        if ((ic & (KS - 1)) == KS - 1)       // chunk complete -> publish
                            __hip_atomic_store(&fb_p[ic >> 3], 1, __ATOMIC_RELEASE,
                                               __HIP_MEMORY_SCOPE_AGENT);
                    }
                }
            }
        }

        if (is_consumer) {
#pragma unroll
            for (int i = 0; i < KS; ++i) rlg_cur[i] = rlg_next[i];
        }
        __syncthreads();
    }

    if (g == G - 1 && tid == NTH - 1) sdtw_out[b] = result;   // cell (1023,1023)
}

// ---------------- fallback (proven R6 single-block-per-batch) ----------------
#define FB_WAVES 8
#define FB_NTH 512
#define FB_DOW 71
#define FB_TOT (FB_DOW * 7 + 63 + 1024)   // 1584
#define FB_NB (FB_TOT / 8)                // 198

__global__ __launch_bounds__(FB_NTH) void sdtw_fb(const float* __restrict__ pred,
                                                  const float* __restrict__ targ,
                                                  float* __restrict__ sdtw_out) {
    __shared__ float p[T];
    __shared__ float ring[FB_WAVES - 1][1024];
    const int b = blockIdx.x;
    const int tid = threadIdx.x;
    const int wv = tid >> 6, ln = tid & 63;
    const int myoff = FB_DOW * wv + ln;
    ((float2*)p)[tid] = ((const float2*)(pred + b * T))[tid];
    const float2 t2v = ((const float2*)(targ + b * T))[tid];
    const float tj0 = t2v.x, tj1 = t2v.y;
    float top0 = BIGF, top1 = BIGF, cornerR = BIGF, rc = BIGF, result = 0.0f;
    __syncthreads();
    for (int sb = 0; sb < FB_NB; ++sb) {
        const int ics = sb * 8 - myoff;
        float rl[8];
#pragma unroll
        for (int so = 0; so < 8; ++so) rl[so] = BIGF;
        if (wv > 0 && ln == 0) {
#pragma unroll
            for (int so = 0; so < 8; ++so) {
                int icc = ics + so;
                icc = icc < 0 ? 0 : (icc >= 1024 ? 1023 : icc);
                rl[so] = ring[wv - 1][icc];
            }
        }
#pragma unroll
        for (int so = 0; so < 8; ++so) {
            const int ic = ics + so;
            const float sh = __shfl_up(rc, 1, 64);
            const float lf0 = (ln == 0) ? rl[so] : sh;
            if (ic >= 0 && ic < 1024) {
                float t0, t1, cc;
                if (ic == 0) { t0 = BIGF; t1 = BIGF; cc = (tid == 0) ? 0.0f : BIGF; }
                else { t0 = top0; t1 = top1; cc = cornerR; }
                const float pr = p[ic];
                const float d0 = pr - tj0;
                const float c00 = fmaf(d0, d0, softmin3(cc, t0, lf0));
                const float d1 = pr - tj1;
                const float c01 = fmaf(d1, d1, softmin3(t0, t1, c00));
                rc = c01; top0 = c00; top1 = c01; cornerR = lf0; result = c01;
                if (ln == 63 && wv < FB_WAVES - 1) ring[wv][ic] = c01;
            }
        }
        __syncthreads();
    }
    if (tid == FB_NTH - 1) sdtw_out[b] = result;
}

// Single block: QTSE reduction over all B*T elements + combine.
__global__ __launch_bounds__(1024) void finish_kernel(const float* __restrict__ pred,
                                                      const float* __restrict__ targ,
                                                      const float* __restrict__ sdtw,
                                                      float* __restrict__ out) {
    const int tid = threadIdx.x;
    float acc = 0.0f;
    for (int idx = tid; idx < BATCH * T; idx += 1024) {
        const float e = pred[idx] - targ[idx];
        acc += e * e * __expf(KQTSE_ * e);
    }
    for (int off = 32; off; off >>= 1) acc += __shfl_down(acc, off, 64);
    __shared__ float red[16];
    const int wave = tid >> 6, lane = tid & 63;
    if (lane == 0) red[wave] = acc;
    __syncthreads();
    if (tid == 0) {
        float q = 0.0f;
        for (int w = 0; w < 16; ++w) q += red[w];
        q /= (float)(BATCH * T);
        float s = 0.0f;
        for (int bb = 0; bb < BATCH; ++bb) s += sdtw[bb];
        s /= (float)BATCH;
        out[0] = 0.1f * s + 1.0f * q;
    }
}

extern "C" void kernel_launch(void* const* d_in, const int* in_sizes, int n_in,
                              void* d_out, int out_size, void* d_ws, size_t ws_size,
                              hipStream_t stream) {
    const float* pred = (const float*)d_in[0];
    const float* targ = (const float*)d_in[1];
    float* out = (float*)d_out;

    if (ws_size >= WS_NEEDED) {
        float* edges = (float*)d_ws;
        int* flags = (int*)((char*)d_ws + FLAG_OFF);
        float* sdtw = (float*)((char*)d_ws + SDTW_OFF);
        reset_kernel<<<(FLAG_INTS + 255) / 256, 256, 0, stream>>>(flags);
        sdtw_pipe_kernel<<<BATCH * G, NTH, 0, stream>>>(pred, targ, edges, flags, sdtw);
        finish_kernel<<<1, 1024, 0, stream>>>(pred, targ, sdtw, out);
    } else {
        float* sdtw = (float*)d_ws;   // 32 floats
        sdtw_fb<<<BATCH, FB_NTH, 0, stream>>>(pred, targ, sdtw);
        finish_kernel<<<1, 1024, 0, stream>>>(pred, targ, sdtw, out);
    }
}

// Round 9
// 428.657 us; speedup vs baseline: 2.2179x; 2.2179x over previous
//
#include <hip/hip_runtime.h>
#include <hip/hip_bf16.h>

#define BATCH 32
#define T 1024
#define G 4                        // pipeline stages (blocks) per batch
#define CPB (T / G)                // 256 columns per stage, 1 col/thread
#define NTH 256
#define WVS 4
#define KS 8                       // steps per barrier window = rows per chunk
#define DOW 75                     // inter-wave offset: >=63+KS, and 3*DOW+63 ≡ 0 (mod 8)
#define SKEW (DOW * (WVS - 1) + 63)   // 288 (8-aligned)
#define TOT (SKEW + T)             // 1312
#define NB (TOT / KS)              // 164 windows
#define NCHUNK (T / KS)            // 128 chunks per interface
#define MARGIN 8                   // startup lead (chunks) for jitter immunity
#define SENT_U 0xAAAAAAAAu
#define BIGF 1e10f
#define K2f 14.426950408889634f    // 1/(gamma*ln2), gamma=0.1
#define GLN2f 0.0693147180559945f  // gamma*ln2
#define KQTSE_ 0.1f

// workspace layout
#define EDGE_FLOATS (BATCH * (G - 1) * T)   // 98304
#define EDGE_BYTES (EDGE_FLOATS * 4)        // 393216
#define SDTW_OFF EDGE_BYTES
#define WS_NEEDED (size_t)(SDTW_OFF + BATCH * 4)

typedef float f32x4 __attribute__((ext_vector_type(4)));

// Exact softmin_gamma(a,b,c): m - g*ln(1 + 2^{K(m-md)} + 2^{K(m-M)}) (one exp folded)
__device__ __forceinline__ float softmin3(float a, float b, float c) {
    float m  = fminf(fminf(a, b), c);             // v_min3_f32
    float M  = fmaxf(fmaxf(a, b), c);             // v_max3_f32
    float md = __builtin_amdgcn_fmed3f(a, b, c);  // v_med3_f32
    float e1 = exp2f((m - md) * K2f);
    float e2 = exp2f((m - M) * K2f);
    return fmaf(-GLN2f, __log2f(1.0f + e1 + e2), m);
}

// ---- device-coherent transport: sc0 sc1 = read/write through to coherence point ----
__device__ __forceinline__ void issue_load8(const float* base, f32x4& a, f32x4& b) {
    asm volatile("global_load_dwordx4 %0, %2, off sc0 sc1\n\t"
                 "global_load_dwordx4 %1, %2, off offset:16 sc0 sc1"
                 : "=&v"(a), "=&v"(b) : "v"(base));
}
__device__ __forceinline__ void await_load8(f32x4& a, f32x4& b) {
    // tie dest regs through the waitcnt so no use schedules earlier; fence scheduler
    asm volatile("s_waitcnt vmcnt(0)" : "+v"(a), "+v"(b) :: "memory");
    __builtin_amdgcn_sched_barrier(0);
}
__device__ __forceinline__ bool has_sent(const f32x4& a, const f32x4& b) {
    return (__float_as_uint(a.x) == SENT_U) | (__float_as_uint(a.y) == SENT_U) |
           (__float_as_uint(a.z) == SENT_U) | (__float_as_uint(a.w) == SENT_U) |
           (__float_as_uint(b.x) == SENT_U) | (__float_as_uint(b.y) == SENT_U) |
           (__float_as_uint(b.z) == SENT_U) | (__float_as_uint(b.w) == SENT_U);
}
__device__ __forceinline__ void spin_load8(const float* base, f32x4& a, f32x4& b) {
    issue_load8(base, a, b);
    await_load8(a, b);
    while (has_sent(a, b)) {
        __builtin_amdgcn_s_sleep(8);
        issue_load8(base, a, b);
        await_load8(a, b);
    }
}
__device__ __forceinline__ void store_edge8(float* base, const f32x4& a, const f32x4& b) {
    asm volatile("global_store_dwordx4 %0, %1, off sc0 sc1\n\t"
                 "global_store_dwordx4 %0, %2, off offset:16 sc0 sc1"
                 :: "v"(base), "v"(a), "v"(b) : "memory");
}

// Cross-block pipelined wave-systolic soft-DTW, sentinel-validated transport.
// Block (b,g) owns columns [g*256,(g+1)*256), 1 col/thread, 4 waves. Intra-block:
// shfl left edges + LDS ring + 1 barrier per KS=8 steps (proven R5/R6 scheme;
// DOW=75 keeps the ordering proof: writer step <= reader window start - 5).
// Inter-block: stage g-1's rightmost column streams to stage g via sentinel-
// prefilled global chunks; consumer issues next-chunk loads BEFORE the window's
// compute and validates after (L3 RTT hidden under ~8 cells of softmin work).
__global__ __launch_bounds__(NTH) void sdtw_pipe(const float* __restrict__ pred,
                                                 const float* __restrict__ targ,
                                                 float* __restrict__ edges,
                                                 float* __restrict__ sdtw_out) {
    __shared__ float p[T];
    __shared__ float ring[WVS - 1][T];

    const int blk = blockIdx.x;
    const int b = blk & (BATCH - 1);   // stages of one batch: blk ≡ b (mod 32)
    const int g = blk >> 5;
    const int tid = threadIdx.x;
    const int wv = tid >> 6;
    const int ln = tid & 63;
    const int myoff = DOW * wv + ln;

    ((float4*)p)[tid] = ((const float4*)(pred + b * T))[tid];
    const float tc = targ[b * T + g * CPB + tid];
    const float zcc = (g == 0 && tid == 0) ? 0.0f : BIGF;   // R[0][0]=0 else BIG

    const float* eb_c = (g > 0) ? (edges + (b * (G - 1) + (g - 1)) * T) : edges;
    float* eb_p = (g < G - 1) ? (edges + (b * (G - 1) + g) * T) : edges;
    const bool consumer = (g > 0) && (tid == 0);
    const bool producing = (g < G - 1) && (wv == WVS - 1) && (ln == 63);

    float top = BIGF, corner = BIGF, rc = BIGF, result = 0.0f;
    float rlg[KS];
#pragma unroll
    for (int i = 0; i < KS; ++i) rlg[i] = BIGF;

    __syncthreads();

    if (consumer) {
        f32x4 a, b4;
        spin_load8(eb_c + (MARGIN - 1) * KS, a, b4);   // establish startup lead
        spin_load8(eb_c, a, b4);                       // chunk 0 (ready by now)
        rlg[0] = a.x; rlg[1] = a.y; rlg[2] = a.z; rlg[3] = a.w;
        rlg[4] = b4.x; rlg[5] = b4.y; rlg[6] = b4.z; rlg[7] = b4.w;
    }

    for (int sb = 0; sb < NB; ++sb) {
        const int ics = sb * KS - myoff;

        // left-edge source for lane 0 of each wave this window
        float rl[KS];
#pragma unroll
        for (int so = 0; so < KS; ++so) rl[so] = BIGF;
        if (ln == 0) {
            if (wv == 0) {
#pragma unroll
                for (int so = 0; so < KS; ++so) rl[so] = rlg[so];
            } else {
#pragma unroll
                for (int so = 0; so < KS; ++so) rl[so] = ring[wv - 1][(ics + so) & (T - 1)];
            }
        }

        // batch-prefetch this window's p values (off the dependence chain)
        float pv[KS];
#pragma unroll
        for (int so = 0; so < KS; ++so) pv[so] = p[(ics + so) & (T - 1)];

        // consumer: issue next chunk's loads now, validate after compute
        f32x4 na, nb4;
        const bool want = consumer && (sb + 1) < NCHUNK;
        const float* basep = eb_c + (sb + 1) * KS;
        if (want) issue_load8(basep, na, nb4);

        float erow[KS];
#pragma unroll
        for (int so = 0; so < KS; ++so) {
            const int ic = ics + so;
            const float sh = __shfl_up(rc, 1, 64);
            const float lfw = (ln == 0) ? rl[so] : sh;
            if ((unsigned)ic < (unsigned)T) {
                const float t0 = (ic == 0) ? BIGF : top;
                const float cc = (ic == 0) ? zcc : corner;
                const float d = pv[so] - tc;
                const float cell = fmaf(d, d, softmin3(cc, t0, lfw));
                rc = cell; top = cell; corner = lfw; result = cell;
                if (ln == 63) {
                    if (wv < WVS - 1) ring[wv][ic] = cell;
                    else erow[so] = cell;
                }
            }
        }

        // producer: publish completed, 32B-aligned chunk (fire-and-forget)
        if (producing && ics >= 0) {
            f32x4 ea = {erow[0], erow[1], erow[2], erow[3]};
            f32x4 eb2 = {erow[4], erow[5], erow[6], erow[7]};
            store_edge8(eb_p + ics, ea, eb2);
        }

        if (want) {
            await_load8(na, nb4);
            while (has_sent(na, nb4)) {          // rare: lead absorbed jitter
                __builtin_amdgcn_s_sleep(2);
                issue_load8(basep, na, nb4);
                await_load8(na, nb4);
            }
            rlg[0] = na.x; rlg[1] = na.y; rlg[2] = na.z; rlg[3] = na.w;
            rlg[4] = nb4.x; rlg[5] = nb4.y; rlg[6] = nb4.z; rlg[7] = nb4.w;
        }
        __syncthreads();
    }

    if (g == G - 1 && tid == NTH - 1) sdtw_out[b] = result;   // cell (1023,1023)
}

// ---------------- fallback (proven R6 single-block-per-batch) ----------------
#define FB_WAVES 8
#define FB_NTH 512
#define FB_DOW 71
#define FB_TOT (FB_DOW * 7 + 63 + 1024)   // 1584
#define FB_NB (FB_TOT / 8)                // 198

__global__ __launch_bounds__(FB_NTH) void sdtw_fb(const float* __restrict__ pred,
                                                  const float* __restrict__ targ,
                                                  float* __restrict__ sdtw_out) {
    __shared__ float p[T];
    __shared__ float ring[FB_WAVES - 1][1024];
    const int b = blockIdx.x;
    const int tid = threadIdx.x;
    const int wv = tid >> 6, ln = tid & 63;
    const int myoff = FB_DOW * wv + ln;
    ((float2*)p)[tid] = ((const float2*)(pred + b * T))[tid];
    const float2 t2v = ((const float2*)(targ + b * T))[tid];
    const float tj0 = t2v.x, tj1 = t2v.y;
    float top0 = BIGF, top1 = BIGF, cornerR = BIGF, rc = BIGF, result = 0.0f;
    __syncthreads();
    for (int sb = 0; sb < FB_NB; ++sb) {
        const int ics = sb * 8 - myoff;
        float rl[8];
#pragma unroll
        for (int so = 0; so < 8; ++so) rl[so] = BIGF;
        if (wv > 0 && ln == 0) {
#pragma unroll
            for (int so = 0; so < 8; ++so) rl[so] = ring[wv - 1][(ics + so) & 1023];
        }
#pragma unroll
        for (int so = 0; so < 8; ++so) {
            const int ic = ics + so;
            const float sh = __shfl_up(rc, 1, 64);
            const float lf0 = (ln == 0) ? rl[so] : sh;
            if ((unsigned)ic < 1024u) {
                float t0, t1, cc;
                if (ic == 0) { t0 = BIGF; t1 = BIGF; cc = (tid == 0) ? 0.0f : BIGF; }
                else { t0 = top0; t1 = top1; cc = cornerR; }
                const float pr = p[ic];
                const float d0 = pr - tj0;
                const float c00 = fmaf(d0, d0, softmin3(cc, t0, lf0));
                const float d1 = pr - tj1;
                const float c01 = fmaf(d1, d1, softmin3(t0, t1, c00));
                rc = c01; top0 = c00; top1 = c01; cornerR = lf0; result = c01;
                if (ln == 63 && wv < FB_WAVES - 1) ring[wv][ic] = c01;
            }
        }
        __syncthreads();
    }
    if (tid == FB_NTH - 1) sdtw_out[b] = result;
}

// Single block: QTSE reduction over all B*T elements + combine.
__global__ __launch_bounds__(1024) void finish_kernel(const float* __restrict__ pred,
                                                      const float* __restrict__ targ,
                                                      const float* __restrict__ sdtw,
                                                      float* __restrict__ out) {
    const int tid = threadIdx.x;
    float acc = 0.0f;
    for (int idx = tid; idx < BATCH * T; idx += 1024) {
        const float e = pred[idx] - targ[idx];
        acc += e * e * __expf(KQTSE_ * e);
    }
    for (int off = 32; off; off >>= 1) acc += __shfl_down(acc, off, 64);
    __shared__ float red[16];
    const int wave = tid >> 6, lane = tid & 63;
    if (lane == 0) red[wave] = acc;
    __syncthreads();
    if (tid == 0) {
        float q = 0.0f;
        for (int w = 0; w < 16; ++w) q += red[w];
        q /= (float)(BATCH * T);
        float s = 0.0f;
        for (int bb = 0; bb < BATCH; ++bb) s += sdtw[bb];
        s /= (float)BATCH;
        out[0] = 0.1f * s + 1.0f * q;
    }
}

extern "C" void kernel_launch(void* const* d_in, const int* in_sizes, int n_in,
                              void* d_out, int out_size, void* d_ws, size_t ws_size,
                              hipStream_t stream) {
    const float* pred = (const float*)d_in[0];
    const float* targ = (const float*)d_in[1];
    float* out = (float*)d_out;

    if (ws_size >= WS_NEEDED) {
        float* edges = (float*)d_ws;
        float* sdtw = (float*)((char*)d_ws + SDTW_OFF);
        hipMemsetAsync(d_ws, 0xAA, EDGE_BYTES, stream);   // sentinel-fill edge buffer
        sdtw_pipe<<<BATCH * G, NTH, 0, stream>>>(pred, targ, edges, sdtw);
        finish_kernel<<<1, 1024, 0, stream>>>(pred, targ, sdtw, out);
    } else {
        float* sdtw = (float*)d_ws;   // 32 floats
        sdtw_fb<<<BATCH, FB_NTH, 0, stream>>>(pred, targ, sdtw);
        finish_kernel<<<1, 1024, 0, stream>>>(pred, targ, sdtw, out);
    }
}